// Round 2
// baseline (717.887 us; speedup 1.0000x reference)
//
#include <hip/hip_runtime.h>
#include <hip/hip_bf16.h>

// Problem constants
#define T_DIM 64
#define B_DIM 512
#define D_DIM 1536
#define H_DIM 1024
#define M_DIM (T_DIM * B_DIM)   // 32768 rows through the MLP
#define DISCOUNT 0.997f
#define LAM 0.95f

// GEMM tiling: 256x256 C-tile, 512 threads (8 waves, 2m x 4n), BK=32.
// QUAD-buffered LDS K-tiles (4 x 32 KB = 128 KB), prefetch depth 3 tiles,
// counted vmcnt(8) at each tile boundary (never drains to 0 in the loop).
// Grid = 128*4 = 512 = exactly 2 rounds of 256 CUs (zero tail).
#define BM 256
#define BN 256
#define BK 32
#define TILES_M (M_DIM / BM)    // 128
#define TILES_N (H_DIM / BN)    // 4
#define N_XCD 8

typedef __bf16 bf16x8 __attribute__((ext_vector_type(8)));
typedef float  f32x4  __attribute__((ext_vector_type(4)));

__device__ __forceinline__ void async_load16(const void* g, void* l) {
    __builtin_amdgcn_global_load_lds(
        (const __attribute__((address_space(1))) void*)g,
        (__attribute__((address_space(3))) void*)l,
        16, 0, 0);
}

__device__ __forceinline__ unsigned short f2bf_raw(float f) {
    __hip_bfloat16 h = __float2bfloat16(f);
    return *reinterpret_cast<unsigned short*>(&h);
}

// ---------------------------------------------------------------------------
// feat fp32 -> bf16, vectorized (float4 in, ushort4 out)
// ---------------------------------------------------------------------------
__global__ __launch_bounds__(256) void cvt_bf16_kernel(
    const float* __restrict__ x, __hip_bfloat16* __restrict__ y, long n4) {
    long i = (long)blockIdx.x * blockDim.x + threadIdx.x;
    if (i >= n4) return;
    float4 v = reinterpret_cast<const float4*>(x)[i];
    ushort4 o;
    o.x = f2bf_raw(v.x);
    o.y = f2bf_raw(v.y);
    o.z = f2bf_raw(v.z);
    o.w = f2bf_raw(v.w);
    reinterpret_cast<ushort4*>(y)[i] = o;
}

// ---------------------------------------------------------------------------
// All 4 weight transposes in one launch. W (K x N fp32) -> Wt (N x K bf16).
// ---------------------------------------------------------------------------
__global__ __launch_bounds__(256) void transpose_cvt_all_kernel(
    const float* __restrict__ W0, const float* __restrict__ W1,
    const float* __restrict__ W2, const float* __restrict__ W3,
    __hip_bfloat16* __restrict__ T0, __hip_bfloat16* __restrict__ T1,
    __hip_bfloat16* __restrict__ T2, __hip_bfloat16* __restrict__ T3) {
    __shared__ float tile[32][33];
    int z = blockIdx.z;
    const float* W;
    __hip_bfloat16* Tt;
    int K;
    if (z == 0)      { W = W0; Tt = T0; K = D_DIM; }
    else if (z == 1) { W = W1; Tt = T1; K = H_DIM; }
    else if (z == 2) { W = W2; Tt = T2; K = H_DIM; }
    else             { W = W3; Tt = T3; K = H_DIM; }
    int k0 = blockIdx.x * 32, n0 = blockIdx.y * 32;
    if (k0 >= K) return;
    int tx = threadIdx.x, ty = threadIdx.y;  // 32 x 8
    #pragma unroll
    for (int r = ty; r < 32; r += 8)
        tile[r][tx] = W[(size_t)(k0 + r) * H_DIM + n0 + tx];
    __syncthreads();
    #pragma unroll
    for (int r = ty; r < 32; r += 8)
        Tt[(size_t)(n0 + r) * K + k0 + tx] = __float2bfloat16(tile[tx][r]);
}

// ---------------------------------------------------------------------------
// C[m][n] = silu( sum_k A[m][k] * Bt[n][k] + bias[n] ), output bf16.
//
// 256x256 tile, 512 threads (8 waves = 2m x 4n), wave tile 128x64.
// BK=32 K-tiles, QUAD-buffered LDS: bufs A[4][256*32], B[4][256*32] = 128 KB.
// Prefetch depth 3: tile t+3's staging (4 global_load_lds/wave) is issued
// during tile t; tile-boundary wait is a COUNTED s_waitcnt vmcnt(8) —
// guarantees tile t's 4 staging instrs (issued 3 iters ago, older than the
// 8 allowed outstanding) have landed, while tiles t+1/t+2 stay in flight
// across the barrier (T4). Tail peels vmcnt(4) / vmcnt(0).
//
// Per iteration (one K-tile): 1 vmcnt + 1 s_barrier + 12 ds_read_b128
// (8 A-frags + 4 B-frags, each read once) + 4 global_load_lds + 32 MFMA.
// WAR safety: stage at iter t writes buf[(t+3)&3] == buf[(t-1)&3]; all
// waves' reads of buf[t-1] completed before their MFMAs (lgkmcnt), which
// precede the barrier at iter t's top, which precedes the stage issue.
//
// LDS swizzle via permuted global source column (BK=32: 4 8-elem groups,
// XOR with row&3): staging loads global[row][c8 ^ (row&3)], fragment reads
// use LDS[row][quad ^ (row&3)] -> conflict-free (8 lanes per 16B bank group
// per b128, perfectly balanced).
// XCD swizzle: 512 blocks, xcd = l%8; nwg%8==0 -> bijective.
// ---------------------------------------------------------------------------
__global__ __launch_bounds__(512, 2) void gemm_silu_kernel(
    const __hip_bfloat16* __restrict__ A,
    const __hip_bfloat16* __restrict__ Bt,
    const float* __restrict__ bias,
    __hip_bfloat16* __restrict__ C,
    int K) {

    __shared__ alignas(16) __hip_bfloat16 lds[65536];   // 128 KB

    const int tid  = threadIdx.x;
    const int wave = tid >> 6;         // 0..7
    const int lane = tid & 63;
    const int quad = lane >> 4;        // 0..3 (k-slice of fragment)
    const int r16  = lane & 15;        // 0..15
    const int wm   = wave & 1;         // wave row in 2x4
    const int wn   = wave >> 1;        // wave col in 2x4 (0..3)

    // XCD-aware tile assignment: 512 blocks = 128 M-tiles x 4 N-tiles
    const int l     = blockIdx.x;
    const int xcd   = l & (N_XCD - 1);
    const int local = l >> 3;                    // 0..63
    const int tn    = local & (TILES_N - 1);     // 0..3
    const int tm    = (xcd << 4) | (local >> 2); // 0..127
    const int m0 = tm * BM;
    const int n0 = tn * BN;

    // --- staging geometry: one global_load_lds covers 16 rows x 32 cols.
    // wave w stages rows w*32 + {0,16}; lane -> row w*32+i*16+(lane>>2),
    // col group lane&3 (8 elems = 16 B). Source col pre-swizzled by row&3.
    const int rsub = lane >> 2;                       // 0..15
    const int cgrp = lane & 3;                        // 0..3
    const int scol = ((cgrp ^ (rsub & 3)) << 3);      // swizzled source col
    const __hip_bfloat16* gA = A  + (size_t)(m0 + wave * 32 + rsub) * K + scol;
    const __hip_bfloat16* gB = Bt + (size_t)(n0 + wave * 32 + rsub) * K + scol;
    const int ldsOf0 = (wave * 32) * 32;              // elems within a buf
    const int ldsOf1 = (wave * 32 + 16) * 32;

    // --- fragment read offsets (elems within a buf), swizzled
    const int swz    = ((quad ^ (r16 & 3)) << 3);
    const int rdoffA = (wm * 128 + r16) * 32 + swz;
    const int rdoffB = (wn * 64  + r16) * 32 + swz;

    f32x4 acc[8][4];
    #pragma unroll
    for (int i = 0; i < 8; ++i)
        #pragma unroll
        for (int j = 0; j < 4; ++j)
            acc[i][j] = (f32x4){0.f, 0.f, 0.f, 0.f};

#define STAGE(tt) do { \
        const int sbb = (tt) & 3; \
        __hip_bfloat16* Ab_ = &lds[sbb * 8192]; \
        __hip_bfloat16* Bb_ = &lds[32768 + sbb * 8192]; \
        const size_t ko_ = (size_t)(tt) * BK; \
        async_load16(gA + ko_,                 Ab_ + ldsOf0); \
        async_load16(gA + ko_ + (size_t)16 * K, Ab_ + ldsOf1); \
        async_load16(gB + ko_,                 Bb_ + ldsOf0); \
        async_load16(gB + ko_ + (size_t)16 * K, Bb_ + ldsOf1); \
    } while (0)

#define BODY(t, VMCNT, DOSTAGE) do { \
        asm volatile("s_waitcnt vmcnt(" #VMCNT ")" ::: "memory"); \
        __builtin_amdgcn_s_barrier(); \
        __builtin_amdgcn_sched_barrier(0); \
        const int bb = (t) & 3; \
        const __hip_bfloat16* Ab = &lds[bb * 8192]; \
        const __hip_bfloat16* Bb = &lds[32768 + bb * 8192]; \
        bf16x8 af[8], bfr[4]; \
        _Pragma("unroll") \
        for (int i = 0; i < 8; ++i) \
            af[i] = *reinterpret_cast<const bf16x8*>(Ab + rdoffA + i * 512); \
        _Pragma("unroll") \
        for (int j = 0; j < 4; ++j) \
            bfr[j] = *reinterpret_cast<const bf16x8*>(Bb + rdoffB + j * 512); \
        if (DOSTAGE) STAGE((t) + 3); \
        __builtin_amdgcn_s_setprio(1); \
        _Pragma("unroll") \
        for (int i = 0; i < 8; ++i) \
            _Pragma("unroll") \
            for (int j = 0; j < 4; ++j) \
                acc[i][j] = __builtin_amdgcn_mfma_f32_16x16x32_bf16( \
                    af[i], bfr[j], acc[i][j], 0, 0, 0); \
        __builtin_amdgcn_s_setprio(0); \
    } while (0)

    // prologue: stage tiles 0..2 (12 wave-instrs outstanding)
    STAGE(0); STAGE(1); STAGE(2);

    const int NT = K / BK;   // 48 or 32
    for (int t = 0; t < NT - 2; ++t)
        BODY(t, 8, (t + 3 < NT));
    BODY(NT - 2, 4, false);
    BODY(NT - 1, 0, false);

#undef STAGE
#undef BODY

    // epilogue: bias + SiLU + bf16 store
    // C/D layout: col = lane&15, row = quad*4 + reg   [verified m89]
    #pragma unroll
    for (int j = 0; j < 4; ++j) {
        const int col = n0 + wn * 64 + j * 16 + r16;
        const float bj = bias[col];
        #pragma unroll
        for (int i = 0; i < 8; ++i) {
            const int row_base = m0 + wm * 128 + i * 16 + quad * 4;
            #pragma unroll
            for (int rr = 0; rr < 4; ++rr) {
                const float v = acc[i][j][rr] + bj;
                const float s = v / (1.f + __expf(-v));
                C[(size_t)(row_base + rr) * H_DIM + col] = __float2bfloat16(s);
            }
        }
    }
}

// ---------------------------------------------------------------------------
// value[m] = sum_n H[m][n] * Wo[n] + bo      (N = 1024 fixed; 1 wave / row)
// ---------------------------------------------------------------------------
__global__ __launch_bounds__(256) void gemv_value_kernel(
    const __hip_bfloat16* __restrict__ H,
    const float* __restrict__ Wo,
    const float* __restrict__ bo_p,
    float* __restrict__ value, int M) {
    int wave = threadIdx.x >> 6, lane = threadIdx.x & 63;
    int row = blockIdx.x * 4 + wave;
    if (row >= M) return;
    const __hip_bfloat16* hrow = H + (size_t)row * H_DIM;
    float sum = 0.f;
    #pragma unroll
    for (int half = 0; half < 2; ++half) {
        int col = half * 512 + lane * 8;
        uint4 raw = *reinterpret_cast<const uint4*>(hrow + col);
        const __hip_bfloat16* hp = reinterpret_cast<const __hip_bfloat16*>(&raw);
        #pragma unroll
        for (int e = 0; e < 8; ++e)
            sum += __bfloat162float(hp[e]) * Wo[col + e];
    }
    #pragma unroll
    for (int off = 32; off > 0; off >>= 1)
        sum += __shfl_down(sum, off, 64);
    if (lane == 0) value[row] = sum + bo_p[0];
}

// ---------------------------------------------------------------------------
// GAE backward scan. value: (T,B) fp32. out: ret (63x512) then baseline.
// ---------------------------------------------------------------------------
__global__ __launch_bounds__(64) void gae_kernel(
    const float* __restrict__ value,
    const float* __restrict__ reward,
    const float* __restrict__ cont,
    float* __restrict__ out) {
    int b = blockIdx.x * blockDim.x + threadIdx.x;
    if (b >= B_DIM) return;
    float adv = 0.f;
    float v_next = value[(T_DIM - 1) * B_DIM + b];
    for (int t = T_DIM - 2; t >= 0; --t) {
        float v_t  = value[t * B_DIM + b];
        float disc = cont[(t + 1) * B_DIM + b] * DISCOUNT;
        float delta = reward[t * B_DIM + b] + disc * v_next - v_t;
        adv = delta + disc * LAM * adv;
        out[t * B_DIM + b] = adv + v_t;                           // ret
        out[(T_DIM - 1) * B_DIM + t * B_DIM + b] = v_t;           // baseline
        v_next = v_t;
    }
}

// ---------------------------------------------------------------------------
extern "C" void kernel_launch(void* const* d_in, const int* in_sizes, int n_in,
                              void* d_out, int out_size, void* d_ws, size_t ws_size,
                              hipStream_t stream) {
    const float* feat   = (const float*)d_in[0];
    const float* reward = (const float*)d_in[1];
    const float* cont   = (const float*)d_in[2];
    const float* W[4]   = {(const float*)d_in[3], (const float*)d_in[5],
                           (const float*)d_in[7], (const float*)d_in[9]};
    const float* bias[4] = {(const float*)d_in[4], (const float*)d_in[6],
                            (const float*)d_in[8], (const float*)d_in[10]};
    const float* Wo = (const float*)d_in[11];
    const float* bo = (const float*)d_in[12];
    float* out = (float*)d_out;

    // workspace layout
    char* ws = (char*)d_ws;
    __hip_bfloat16* Xb = (__hip_bfloat16*)ws; ws += (size_t)M_DIM * D_DIM * 2;   // 96 MB
    __hip_bfloat16* Ha = (__hip_bfloat16*)ws; ws += (size_t)M_DIM * H_DIM * 2;   // 64 MB
    __hip_bfloat16* Hb = (__hip_bfloat16*)ws; ws += (size_t)M_DIM * H_DIM * 2;   // 64 MB
    __hip_bfloat16* Wt0 = (__hip_bfloat16*)ws; ws += (size_t)H_DIM * D_DIM * 2;  // 3 MB
    __hip_bfloat16* Wt1 = (__hip_bfloat16*)ws; ws += (size_t)H_DIM * H_DIM * 2;
    __hip_bfloat16* Wt2 = (__hip_bfloat16*)ws; ws += (size_t)H_DIM * H_DIM * 2;
    __hip_bfloat16* Wt3 = (__hip_bfloat16*)ws; ws += (size_t)H_DIM * H_DIM * 2;
    float* value = (float*)ws; ws += (size_t)M_DIM * 4;

    // 1. feat -> bf16
    long n4 = (long)M_DIM * D_DIM / 4;
    cvt_bf16_kernel<<<(int)((n4 + 255) / 256), 256, 0, stream>>>(feat, Xb, n4);

    // 2. all weight transposes, one launch
    transpose_cvt_all_kernel<<<dim3(D_DIM / 32, H_DIM / 32, 4), dim3(32, 8), 0, stream>>>(
        W[0], W[1], W[2], W[3], Wt0, Wt1, Wt2, Wt3);

    // 3. MLP: 4 GEMM + SiLU layers (1D grid, XCD-swizzled inside)
    const int nblocks = TILES_M * TILES_N;  // 512
    gemm_silu_kernel<<<nblocks, 512, 0, stream>>>(Xb, Wt0, bias[0], Ha, D_DIM);
    gemm_silu_kernel<<<nblocks, 512, 0, stream>>>(Ha, Wt1, bias[1], Hb, H_DIM);
    gemm_silu_kernel<<<nblocks, 512, 0, stream>>>(Hb, Wt2, bias[2], Ha, H_DIM);
    gemm_silu_kernel<<<nblocks, 512, 0, stream>>>(Ha, Wt3, bias[3], Hb, H_DIM);

    // 4. value head GEMV
    gemv_value_kernel<<<M_DIM / 4, 256, 0, stream>>>(Hb, Wo, bo, value, M_DIM);

    // 5. GAE scan
    gae_kernel<<<8, 64, 0, stream>>>(value, reward, cont, out);
}

// Round 3
// 686.775 us; speedup vs baseline: 1.0453x; 1.0453x over previous
//
#include <hip/hip_runtime.h>
#include <hip/hip_bf16.h>

// Problem constants
#define T_DIM 64
#define B_DIM 512
#define D_DIM 1536
#define H_DIM 1024
#define M_DIM (T_DIM * B_DIM)   // 32768 rows through the MLP
#define DISCOUNT 0.997f
#define LAM 0.95f

// GEMM tiling: 256x256 C-tile, 512 threads (8 waves, 2m x 4n), BK=32.
// QUAD-buffered LDS K-tiles (4 x 32 KB = 128 KB), prefetch depth 3 tiles,
// counted vmcnt(8) at each tile boundary (never drains to 0 in the loop).
// Grid = 128*4 = 512 = exactly 2 rounds of 256 CUs (zero tail).
#define BM 256
#define BN 256
#define BK 32
#define TILES_M (M_DIM / BM)    // 128
#define TILES_N (H_DIM / BN)    // 4
#define N_XCD 8

typedef __bf16 bf16x8 __attribute__((ext_vector_type(8)));
typedef float  f32x4  __attribute__((ext_vector_type(4)));

__device__ __forceinline__ void async_load16(const void* g, void* l) {
    __builtin_amdgcn_global_load_lds(
        (const __attribute__((address_space(1))) void*)g,
        (__attribute__((address_space(3))) void*)l,
        16, 0, 0);
}

__device__ __forceinline__ unsigned short f2bf_raw(float f) {
    __hip_bfloat16 h = __float2bfloat16(f);
    return *reinterpret_cast<unsigned short*>(&h);
}

// ---------------------------------------------------------------------------
// feat fp32 -> bf16, vectorized (float4 in, ushort4 out)
// ---------------------------------------------------------------------------
__global__ __launch_bounds__(256) void cvt_bf16_kernel(
    const float* __restrict__ x, __hip_bfloat16* __restrict__ y, long n4) {
    long i = (long)blockIdx.x * blockDim.x + threadIdx.x;
    if (i >= n4) return;
    float4 v = reinterpret_cast<const float4*>(x)[i];
    ushort4 o;
    o.x = f2bf_raw(v.x);
    o.y = f2bf_raw(v.y);
    o.z = f2bf_raw(v.z);
    o.w = f2bf_raw(v.w);
    reinterpret_cast<ushort4*>(y)[i] = o;
}

// ---------------------------------------------------------------------------
// All 4 weight transposes in one launch. W (K x N fp32) -> Wt (N x K bf16).
// ---------------------------------------------------------------------------
__global__ __launch_bounds__(256) void transpose_cvt_all_kernel(
    const float* __restrict__ W0, const float* __restrict__ W1,
    const float* __restrict__ W2, const float* __restrict__ W3,
    __hip_bfloat16* __restrict__ T0, __hip_bfloat16* __restrict__ T1,
    __hip_bfloat16* __restrict__ T2, __hip_bfloat16* __restrict__ T3) {
    __shared__ float tile[32][33];
    int z = blockIdx.z;
    const float* W;
    __hip_bfloat16* Tt;
    int K;
    if (z == 0)      { W = W0; Tt = T0; K = D_DIM; }
    else if (z == 1) { W = W1; Tt = T1; K = H_DIM; }
    else if (z == 2) { W = W2; Tt = T2; K = H_DIM; }
    else             { W = W3; Tt = T3; K = H_DIM; }
    int k0 = blockIdx.x * 32, n0 = blockIdx.y * 32;
    if (k0 >= K) return;
    int tx = threadIdx.x, ty = threadIdx.y;  // 32 x 8
    #pragma unroll
    for (int r = ty; r < 32; r += 8)
        tile[r][tx] = W[(size_t)(k0 + r) * H_DIM + n0 + tx];
    __syncthreads();
    #pragma unroll
    for (int r = ty; r < 32; r += 8)
        Tt[(size_t)(n0 + r) * K + k0 + tx] = __float2bfloat16(tile[tx][r]);
}

// ---------------------------------------------------------------------------
// C[m][n] = silu( sum_k A[m][k] * Bt[n][k] + bias[n] ), output bf16.
//
// 256x256 tile, 512 threads (8 waves = 2m x 4n), wave tile 128x64.
// BK=32 K-tiles, QUAD-buffered LDS (128 KB), prefetch depth 3, counted
// vmcnt(8) per tile boundary (tiles t+1,t+2 stay in flight across the
// barrier; vmcnt precedes s_barrier so after the barrier ALL waves' tile-t
// stages are complete). Tail peels vmcnt(4)/vmcnt(0).
//
// Swizzle (BK=32 row = 64 B = 4 granules of 16 B): granule = (4*row +
// colgrp) mod 8 = 4*(row&1) + colgrp. Using colgrp = quad ^ ((row>>1)&3)
// spreads each 16-lane read group over all 8 granules exactly 2x (2-way =
// free, m136). Round-2's (row&3) only alternated granules {0,4}+xor ->
// 4-way conflicts (9.4M measured). Staging source column uses the SAME
// permutation (both-sides-or-neither).
//
// Body = 4 read/MFMA sub-phases pinned with sched_barrier(0): reads for
// cluster p+1 issue before cluster p's MFMAs; setprio(1) around MFMA only.
// Lockstep-broken waves overlap one wave's ds_reads with another's MFMAs.
//
// MFMA operands SWAPPED: acc = mfma(bfr, af) computes the C^T fragment:
// lane&15 = m, regs = 4 consecutive n. Epilogue packs 4 bf16 cols into one
// 8-B ushort4 store (round-2's 2-B scatter gave 2.1x HBM write-amp).
// ---------------------------------------------------------------------------
__global__ __launch_bounds__(512, 2) void gemm_silu_kernel(
    const __hip_bfloat16* __restrict__ A,
    const __hip_bfloat16* __restrict__ Bt,
    const float* __restrict__ bias,
    __hip_bfloat16* __restrict__ C,
    int K) {

    __shared__ alignas(16) __hip_bfloat16 lds[65536];   // 128 KB

    const int tid  = threadIdx.x;
    const int wave = tid >> 6;         // 0..7
    const int lane = tid & 63;
    const int quad = lane >> 4;        // 0..3 (k-slice of fragment)
    const int r16  = lane & 15;        // 0..15
    const int wm   = wave & 1;         // wave row in 2x4
    const int wn   = wave >> 1;        // wave col in 2x4 (0..3)

    // XCD-aware tile assignment: 512 blocks = 128 M-tiles x 4 N-tiles
    const int l     = blockIdx.x;
    const int xcd   = l & (N_XCD - 1);
    const int local = l >> 3;                    // 0..63
    const int tn    = local & (TILES_N - 1);     // 0..3
    const int tm    = (xcd << 4) | (local >> 2); // 0..127
    const int m0 = tm * BM;
    const int n0 = tn * BN;

    // --- staging geometry: one global_load_lds covers 16 rows x 32 cols.
    // lane -> row lane>>2, col group lane&3. Source col pre-swizzled with
    // s(row) = (row>>1)&3 (row bits 1:2 -> granule bits, see header).
    const int rsub = lane >> 2;                       // 0..15
    const int cgrp = lane & 3;                        // 0..3
    const int scol = ((cgrp ^ ((rsub >> 1) & 3)) << 3);
    const __hip_bfloat16* gA = A  + (size_t)(m0 + wave * 32 + rsub) * K + scol;
    const __hip_bfloat16* gB = Bt + (size_t)(n0 + wave * 32 + rsub) * K + scol;
    const int ldsOf0 = (wave * 32) * 32;              // elems within a buf
    const int ldsOf1 = (wave * 32 + 16) * 32;

    // --- fragment read offsets (elems within a buf), swizzled to match
    const int swz    = ((quad ^ ((r16 >> 1) & 3)) << 3);
    const int rdoffA = (wm * 128 + r16) * 32 + swz;
    const int rdoffB = (wn * 64  + r16) * 32 + swz;

    f32x4 acc[8][4];
    #pragma unroll
    for (int i = 0; i < 8; ++i)
        #pragma unroll
        for (int j = 0; j < 4; ++j)
            acc[i][j] = (f32x4){0.f, 0.f, 0.f, 0.f};

#define STAGE(tt) do { \
        const int sbb = (tt) & 3; \
        __hip_bfloat16* Ab_ = &lds[sbb * 8192]; \
        __hip_bfloat16* Bb_ = &lds[32768 + sbb * 8192]; \
        const size_t ko_ = (size_t)(tt) * BK; \
        async_load16(gA + ko_,                  Ab_ + ldsOf0); \
        async_load16(gA + ko_ + (size_t)16 * K, Ab_ + ldsOf1); \
        async_load16(gB + ko_,                  Bb_ + ldsOf0); \
        async_load16(gB + ko_ + (size_t)16 * K, Bb_ + ldsOf1); \
    } while (0)

#define RD_A(i) (*reinterpret_cast<const bf16x8*>(Ab + rdoffA + (i) * 512))
#define RD_B(j) (*reinterpret_cast<const bf16x8*>(Bb + rdoffB + (j) * 512))

// Cᵀ accumulation: mfma(B-rows, A-rows) -> lane&15 = m, regs = n
#define MM(i, areg) do { \
        acc[i][0] = __builtin_amdgcn_mfma_f32_16x16x32_bf16(b0, areg, acc[i][0], 0, 0, 0); \
        acc[i][1] = __builtin_amdgcn_mfma_f32_16x16x32_bf16(b1, areg, acc[i][1], 0, 0, 0); \
        acc[i][2] = __builtin_amdgcn_mfma_f32_16x16x32_bf16(b2, areg, acc[i][2], 0, 0, 0); \
        acc[i][3] = __builtin_amdgcn_mfma_f32_16x16x32_bf16(b3, areg, acc[i][3], 0, 0, 0); \
    } while (0)

#define BODY(t, VMCNT, DOSTAGE) do { \
        asm volatile("s_waitcnt vmcnt(" #VMCNT ")" ::: "memory"); \
        __builtin_amdgcn_s_barrier(); \
        __builtin_amdgcn_sched_barrier(0); \
        if (DOSTAGE) STAGE((t) + 3); \
        const int bb = (t) & 3; \
        const __hip_bfloat16* Ab = &lds[bb * 8192]; \
        const __hip_bfloat16* Bb = &lds[32768 + bb * 8192]; \
        bf16x8 b0 = RD_B(0), b1 = RD_B(1), b2 = RD_B(2), b3 = RD_B(3); \
        bf16x8 a0 = RD_A(0), a1 = RD_A(1), a2 = RD_A(2), a3 = RD_A(3); \
        __builtin_amdgcn_s_setprio(1); MM(0, a0); MM(1, a1); __builtin_amdgcn_s_setprio(0); \
        __builtin_amdgcn_sched_barrier(0); \
        a0 = RD_A(4); a1 = RD_A(5); \
        __builtin_amdgcn_s_setprio(1); MM(2, a2); MM(3, a3); __builtin_amdgcn_s_setprio(0); \
        __builtin_amdgcn_sched_barrier(0); \
        a2 = RD_A(6); a3 = RD_A(7); \
        __builtin_amdgcn_s_setprio(1); MM(4, a0); MM(5, a1); __builtin_amdgcn_s_setprio(0); \
        __builtin_amdgcn_sched_barrier(0); \
        __builtin_amdgcn_s_setprio(1); MM(6, a2); MM(7, a3); __builtin_amdgcn_s_setprio(0); \
    } while (0)

    // prologue: stage tiles 0..2 (12 wave-instrs outstanding)
    STAGE(0); STAGE(1); STAGE(2);

    const int NT = K / BK;   // 48 or 32
    for (int t = 0; t < NT - 2; ++t)
        BODY(t, 8, (t + 3 < NT));
    BODY(NT - 2, 4, false);
    BODY(NT - 1, 0, false);

#undef STAGE
#undef RD_A
#undef RD_B
#undef MM
#undef BODY

    // epilogue: bias + SiLU + packed 8-B stores.
    // Cᵀ fragment layout: m = lane&15 (block i), n = j*16 + quad*4 + rr.
    #pragma unroll
    for (int j = 0; j < 4; ++j) {
        const int c0 = n0 + wn * 64 + j * 16 + quad * 4;
        const float4 b4 = *reinterpret_cast<const float4*>(&bias[c0]);
        const float* bp = reinterpret_cast<const float*>(&b4);
        #pragma unroll
        for (int i = 0; i < 8; ++i) {
            const int row = m0 + wm * 128 + i * 16 + r16;
            ushort4 o;
            unsigned short* op = reinterpret_cast<unsigned short*>(&o);
            #pragma unroll
            for (int rr = 0; rr < 4; ++rr) {
                const float v = acc[i][j][rr] + bp[rr];
                const float s = v / (1.f + __expf(-v));
                op[rr] = f2bf_raw(s);
            }
            *reinterpret_cast<ushort4*>(&C[(size_t)row * H_DIM + c0]) = o;
        }
    }
}

// ---------------------------------------------------------------------------
// value[m] = sum_n H[m][n] * Wo[n] + bo      (N = 1024 fixed; 1 wave / row)
// ---------------------------------------------------------------------------
__global__ __launch_bounds__(256) void gemv_value_kernel(
    const __hip_bfloat16* __restrict__ H,
    const float* __restrict__ Wo,
    const float* __restrict__ bo_p,
    float* __restrict__ value, int M) {
    int wave = threadIdx.x >> 6, lane = threadIdx.x & 63;
    int row = blockIdx.x * 4 + wave;
    if (row >= M) return;
    const __hip_bfloat16* hrow = H + (size_t)row * H_DIM;
    float sum = 0.f;
    #pragma unroll
    for (int half = 0; half < 2; ++half) {
        int col = half * 512 + lane * 8;
        uint4 raw = *reinterpret_cast<const uint4*>(hrow + col);
        const __hip_bfloat16* hp = reinterpret_cast<const __hip_bfloat16*>(&raw);
        #pragma unroll
        for (int e = 0; e < 8; ++e)
            sum += __bfloat162float(hp[e]) * Wo[col + e];
    }
    #pragma unroll
    for (int off = 32; off > 0; off >>= 1)
        sum += __shfl_down(sum, off, 64);
    if (lane == 0) value[row] = sum + bo_p[0];
}

// ---------------------------------------------------------------------------
// GAE backward scan. value: (T,B) fp32. out: ret (63x512) then baseline.
// ---------------------------------------------------------------------------
__global__ __launch_bounds__(64) void gae_kernel(
    const float* __restrict__ value,
    const float* __restrict__ reward,
    const float* __restrict__ cont,
    float* __restrict__ out) {
    int b = blockIdx.x * blockDim.x + threadIdx.x;
    if (b >= B_DIM) return;
    float adv = 0.f;
    float v_next = value[(T_DIM - 1) * B_DIM + b];
    for (int t = T_DIM - 2; t >= 0; --t) {
        float v_t  = value[t * B_DIM + b];
        float disc = cont[(t + 1) * B_DIM + b] * DISCOUNT;
        float delta = reward[t * B_DIM + b] + disc * v_next - v_t;
        adv = delta + disc * LAM * adv;
        out[t * B_DIM + b] = adv + v_t;                           // ret
        out[(T_DIM - 1) * B_DIM + t * B_DIM + b] = v_t;           // baseline
        v_next = v_t;
    }
}

// ---------------------------------------------------------------------------
extern "C" void kernel_launch(void* const* d_in, const int* in_sizes, int n_in,
                              void* d_out, int out_size, void* d_ws, size_t ws_size,
                              hipStream_t stream) {
    const float* feat   = (const float*)d_in[0];
    const float* reward = (const float*)d_in[1];
    const float* cont   = (const float*)d_in[2];
    const float* W[4]   = {(const float*)d_in[3], (const float*)d_in[5],
                           (const float*)d_in[7], (const float*)d_in[9]};
    const float* bias[4] = {(const float*)d_in[4], (const float*)d_in[6],
                            (const float*)d_in[8], (const float*)d_in[10]};
    const float* Wo = (const float*)d_in[11];
    const float* bo = (const float*)d_in[12];
    float* out = (float*)d_out;

    // workspace layout
    char* ws = (char*)d_ws;
    __hip_bfloat16* Xb = (__hip_bfloat16*)ws; ws += (size_t)M_DIM * D_DIM * 2;   // 96 MB
    __hip_bfloat16* Ha = (__hip_bfloat16*)ws; ws += (size_t)M_DIM * H_DIM * 2;   // 64 MB
    __hip_bfloat16* Hb = (__hip_bfloat16*)ws; ws += (size_t)M_DIM * H_DIM * 2;   // 64 MB
    __hip_bfloat16* Wt0 = (__hip_bfloat16*)ws; ws += (size_t)H_DIM * D_DIM * 2;  // 3 MB
    __hip_bfloat16* Wt1 = (__hip_bfloat16*)ws; ws += (size_t)H_DIM * H_DIM * 2;
    __hip_bfloat16* Wt2 = (__hip_bfloat16*)ws; ws += (size_t)H_DIM * H_DIM * 2;
    __hip_bfloat16* Wt3 = (__hip_bfloat16*)ws; ws += (size_t)H_DIM * H_DIM * 2;
    float* value = (float*)ws; ws += (size_t)M_DIM * 4;

    // 1. feat -> bf16
    long n4 = (long)M_DIM * D_DIM / 4;
    cvt_bf16_kernel<<<(int)((n4 + 255) / 256), 256, 0, stream>>>(feat, Xb, n4);

    // 2. all weight transposes, one launch
    transpose_cvt_all_kernel<<<dim3(D_DIM / 32, H_DIM / 32, 4), dim3(32, 8), 0, stream>>>(
        W[0], W[1], W[2], W[3], Wt0, Wt1, Wt2, Wt3);

    // 3. MLP: 4 GEMM + SiLU layers (1D grid, XCD-swizzled inside)
    const int nblocks = TILES_M * TILES_N;  // 512
    gemm_silu_kernel<<<nblocks, 512, 0, stream>>>(Xb, Wt0, bias[0], Ha, D_DIM);
    gemm_silu_kernel<<<nblocks, 512, 0, stream>>>(Ha, Wt1, bias[1], Hb, H_DIM);
    gemm_silu_kernel<<<nblocks, 512, 0, stream>>>(Hb, Wt2, bias[2], Ha, H_DIM);
    gemm_silu_kernel<<<nblocks, 512, 0, stream>>>(Ha, Wt3, bias[3], Hb, H_DIM);

    // 4. value head GEMV
    gemv_value_kernel<<<M_DIM / 4, 256, 0, stream>>>(Hb, Wo, bo, value, M_DIM);

    // 5. GAE scan
    gae_kernel<<<8, 64, 0, stream>>>(value, reward, cont, out);
}